// Round 1
// baseline (130662.610 us; speedup 1.0000x reference)
//
#include <hip/hip_runtime.h>
#include <math.h>

// ---------------------------------------------------------------------------
// Decoder_21371757265153: sequential label decoder.
// B=16, T=1024, ENC=768, HID=RNN_H=384, 4H=1536, LABELS=33, POS_EMB=128.
//
// Strategy:
//  - precompute encW_lin[b][t][l] = enc[b,t,:] @ W_lin[l,384:]           (GEMM)
//  - precompute posEmbW[p][j]     = posEmb[p,:] @ W_cmb[j,:128]
//  - transpose weights: WT[k][r] (k<384: W_ih, else W_hh), WavgT[k][j]=W_cmb[j,128+k]
//  - sequential kernel: 1 block / sequence; all waves redundantly run the
//    scalar argmax scan (no barriers between events); LSTM matvec only on
//    do_lstm steps, coalesced column-major weight streaming.
// ---------------------------------------------------------------------------

namespace {
constexpr int NB = 16;
constexpr int NT = 1024;
constexpr int NE = 768;
constexpr int NH = 384;
constexpr int NG = 1536;
constexpr int NL = 33;

constexpr int N_WT    = NE * NG;       // 1179648
constexpr int N_WAVGT = NE * NH;       // 294912
constexpr int N_PEW   = 32 * NH;       // 12288
constexpr int N_ENCW  = NB * NT * NL;  // 540672
constexpr int OFF_WAVGT = N_WT;
constexpr int OFF_PEW   = OFF_WAVGT + N_WAVGT;
constexpr int OFF_ENCW  = OFF_PEW + N_PEW;
constexpr int OFF_ST    = OFF_ENCW + N_ENCW;   // h0[384] c0[384] hW0[33]
}

__device__ __forceinline__ float sigmf(float x) { return 1.0f / (1.0f + expf(-x)); }

// Build WT [768][1536], WavgT [768][384], posEmbW [32][384]
__global__ void k_prep(const float* __restrict__ W_ih, const float* __restrict__ W_hh,
                       const float* __restrict__ W_cmb, const float* __restrict__ posEmb,
                       float* __restrict__ ws) {
    float* WT      = ws;
    float* WavgT   = ws + OFF_WAVGT;
    float* posEmbW = ws + OFF_PEW;
    const int n1 = N_WT, n2 = N_WAVGT, n3 = N_PEW;
    for (int i = blockIdx.x * blockDim.x + threadIdx.x; i < n1 + n2 + n3;
         i += gridDim.x * blockDim.x) {
        if (i < n1) {
            int k = i / NG, r = i % NG;
            WT[i] = (k < NH) ? W_ih[r * NH + k] : W_hh[r * NH + (k - NH)];
        } else if (i < n1 + n2) {
            int j2 = i - n1;
            int k = j2 / NH, j = j2 % NH;
            WavgT[j2] = W_cmb[j * 896 + 128 + k];
        } else {
            int j3 = i - n1 - n2;
            int p = j3 / NH, j = j3 % NH;
            const float* pe = posEmb + p * 128;
            const float* wr = W_cmb + j * 896;
            float a = 0.f;
            for (int k = 0; k < 128; ++k) a += pe[k] * wr[k];
            posEmbW[j3] = a;
        }
    }
}

// encW[bt][l] = enc[bt,:] @ W_lin[l, 384:]
__global__ void k_encw(const float* __restrict__ enc, const float* __restrict__ W_lin,
                       float* __restrict__ encW) {
    int gid = blockIdx.x * blockDim.x + threadIdx.x;
    if (gid >= NB * NT * NL) return;
    int bt = gid / NL, l = gid % NL;
    const float4* e4 = reinterpret_cast<const float4*>(enc + (size_t)bt * NE);
    const float4* w4 = reinterpret_cast<const float4*>(W_lin + l * 1152 + NH);
    float a0 = 0, a1 = 0, a2 = 0, a3 = 0;
    for (int k = 0; k < NE / 4; ++k) {
        float4 e = e4[k], w = w4[k];
        a0 += e.x * w.x; a1 += e.y * w.y; a2 += e.z * w.z; a3 += e.w * w.w;
    }
    encW[gid] = (a0 + a1) + (a2 + a3);
}

// initial h0,c0 = lstm_cell(0,0,0); hW0 = b_lin + W_lin[:, :384] @ h0
__global__ void k_init(const float* __restrict__ b_ih, const float* __restrict__ b_hh,
                       const float* __restrict__ W_lin, const float* __restrict__ b_lin,
                       float* __restrict__ st) {
    __shared__ float sh[NH];
    int j = threadIdx.x;
    if (j < NH) {
        float gi = b_ih[j] + b_hh[j];
        float gf = b_ih[NH + j] + b_hh[NH + j];
        float gg = b_ih[2 * NH + j] + b_hh[2 * NH + j];
        float go = b_ih[3 * NH + j] + b_hh[3 * NH + j];
        float c = sigmf(gf) * 0.f + sigmf(gi) * tanhf(gg);
        float h = sigmf(go) * tanhf(c);
        st[j] = h; st[NH + j] = c; sh[j] = h;
    }
    __syncthreads();
    if (j < NL) {
        float a = 0.f;
        for (int k = 0; k < NH; ++k) a += W_lin[j * 1152 + k] * sh[k];
        st[2 * NH + j] = b_lin[j] + a;
    }
}

// fill all output rows with log_softmax(zeros) = -log(33)
__global__ void k_fill(float* __restrict__ out) {
    int i = blockIdx.x * blockDim.x + threadIdx.x;
    if (i < NB * NT * NL) out[i] = -logf(33.0f);
}

__global__ __launch_bounds__(1024) void k_seq(
    const float* __restrict__ enc, const int* __restrict__ char_sizes,
    const int* __restrict__ label_is_sep, const int* __restrict__ label_pos_id,
    const float* __restrict__ b_ih, const float* __restrict__ b_hh,
    const float* __restrict__ W_lin, const float* __restrict__ b_lin,
    const float* __restrict__ b_cmb, const float* __restrict__ ws,
    float* __restrict__ out) {
    const float* WT      = ws;
    const float* WavgT   = ws + OFF_WAVGT;
    const float* posEmbW = ws + OFF_PEW;
    const float* encW    = ws + OFF_ENCW;
    const float* st0     = ws + OFF_ST;

    __shared__ float sh_h[NH], sh_c[NH], sh_lpeW[NH], sh_hWb[NL];
    __shared__ float sh_avg[NE], sh_xcat[NE], sh_g[NG];
    __shared__ float sh_red[NL * 8];
    __shared__ int sh_issep[NL], sh_posid[NL];

    const int b = blockIdx.x;
    const int tid = threadIdx.x;
    const int lane = tid & 63;
    const int wave = tid >> 6;
    int size = char_sizes[b];
    if (size > NT) size = NT;

    if (tid < NH) { sh_h[tid] = st0[tid]; sh_c[tid] = st0[NH + tid]; sh_lpeW[tid] = 0.f; }
    if (tid < NL) {
        sh_hWb[tid] = st0[2 * NH + tid];
        sh_issep[tid] = label_is_sep[tid];
        sh_posid[tid] = label_pos_id[tid];
    }
    __syncthreads();

    int wlen = 0, nw = 0, npos = 0, plast = 0, lpe_pend = -1;
    const float* encWb = encW + b * NT * NL;
    float* outb = out + b * NT * NL;

    for (int t = 0; t < size; ++t) {
        // --- logits + argmax (redundant in every wave; lanes 0..32 active) ---
        float ot = -INFINITY;
        if (lane < NL) ot = tanhf(encWb[t * NL + lane] + sh_hWb[lane]);
        float bv = ot; int bi = lane;
        #pragma unroll
        for (int d = 32; d > 0; d >>= 1) {
            float ov = __shfl_xor(bv, d);
            int   oi = __shfl_xor(bi, d);
            if (ov > bv || (ov == bv && oi < bi)) { bv = ov; bi = oi; }
        }
        const int aid = bi;
        // --- log-softmax output (wave 0 stores) ---
        float ex = (lane < NL) ? expf(ot - bv) : 0.f;
        float s = ex;
        #pragma unroll
        for (int d = 32; d > 0; d >>= 1) s += __shfl_xor(s, d);
        if (wave == 0 && lane < NL) outb[t * NL + lane] = (ot - bv) - logf(s);

        // --- scalar state update (uniform across all threads) ---
        const int issep = sh_issep[aid];
        const int wl_prev = wlen;
        int nw_new;
        if (issep) { npos += 1; nw_new = nw + 1; }
        else       { nw_new = (nw < 1) ? 1 : nw; }
        const int do_l = issep && (nw_new >= 2);
        if (issep && npos >= 2) lpe_pend = plast;
        if (issep) plast = sh_posid[aid];
        wlen = issep ? 1 : wlen + 1;
        nw = nw_new;

        if (do_l) {
            // ================== LSTM event ==================
            int start = t - wl_prev; if (start < 0) start = 0;
            const float denom = (float)((wl_prev < 1) ? 1 : wl_prev);
            __syncthreads();
            // phase 1: avg over enc[start..t) ; lazy lpeW update
            if (tid < NE) {
                float a = 0.f;
                const float* ep = enc + ((size_t)(b * NT + start)) * NE + tid;
                for (int r = start; r < t; ++r) { a += *ep; ep += NE; }
                sh_avg[tid] = a / denom;
            } else if (lpe_pend >= 0) {
                for (int j = tid - NE; j < NH; j += 256)
                    sh_lpeW[j] = posEmbW[lpe_pend * NH + j];
            }
            __syncthreads();
            // phase 2: lwp = tanh(lpeW + WavgT^T avg + b_cmb); xcat = [lwp, h]
            if (tid < NH) {
                const float* wp = WavgT + tid;
                float a0 = 0, a1 = 0, a2 = 0, a3 = 0;
                for (int k = 0; k < NE; k += 4) {
                    a0 += wp[0]        * sh_avg[k];
                    a1 += wp[NH]       * sh_avg[k + 1];
                    a2 += wp[2 * NH]   * sh_avg[k + 2];
                    a3 += wp[3 * NH]   * sh_avg[k + 3];
                    wp += 4 * NH;
                }
                float aw = (a0 + a1) + (a2 + a3);
                sh_xcat[tid]      = tanhf(sh_lpeW[tid] + aw + b_cmb[tid]);
                sh_xcat[NH + tid] = sh_h[tid];
            }
            __syncthreads();
            // phase 3: g = WT^T xcat + b_ih + b_hh  (coalesced float4 rows)
            if (tid < NH) {
                const int r4 = tid * 4;
                const float* wp = WT + r4;
                float4 ai = {0, 0, 0, 0};
                for (int k = 0; k < NH; ++k) {
                    float x = sh_xcat[k];
                    float4 w = *(const float4*)wp; wp += NG;
                    ai.x += w.x * x; ai.y += w.y * x; ai.z += w.z * x; ai.w += w.w * x;
                }
                float4 ah = {0, 0, 0, 0};
                for (int k = NH; k < NE; ++k) {
                    float x = sh_xcat[k];
                    float4 w = *(const float4*)wp; wp += NG;
                    ah.x += w.x * x; ah.y += w.y * x; ah.z += w.z * x; ah.w += w.w * x;
                }
                float4 bi4 = *(const float4*)(b_ih + r4);
                float4 bh4 = *(const float4*)(b_hh + r4);
                sh_g[r4 + 0] = ((ai.x + bi4.x) + ah.x) + bh4.x;
                sh_g[r4 + 1] = ((ai.y + bi4.y) + ah.y) + bh4.y;
                sh_g[r4 + 2] = ((ai.z + bi4.z) + ah.z) + bh4.z;
                sh_g[r4 + 3] = ((ai.w + bi4.w) + ah.w) + bh4.w;
            }
            __syncthreads();
            // phase 4: gate nonlinearities, commit c,h
            if (tid < NH) {
                float gi = sh_g[tid], gf = sh_g[NH + tid];
                float gg = sh_g[2 * NH + tid], go = sh_g[3 * NH + tid];
                float c2 = sigmf(gf) * sh_c[tid] + sigmf(gi) * tanhf(gg);
                float h2 = sigmf(go) * tanhf(c2);
                sh_c[tid] = c2; sh_h[tid] = h2;
            }
            __syncthreads();
            // phase 5: hWb = b_lin + W_lin[:, :384] @ h   (33 rows x 8 partials)
            if (tid < NL * 8) {
                const int l = tid >> 3, p = tid & 7;
                const float* wr = W_lin + l * 1152 + p * 48;
                const float* hp = sh_h + p * 48;
                float a = 0.f;
                #pragma unroll 4
                for (int k = 0; k < 48; ++k) a += wr[k] * hp[k];
                sh_red[tid] = a;
            }
            __syncthreads();
            if (tid < NL) {
                float q = 0.f;
                #pragma unroll
                for (int p = 0; p < 8; ++p) q += sh_red[tid * 8 + p];
                sh_hWb[tid] = b_lin[tid] + q;
            }
            lpe_pend = -1;
            __syncthreads();
        }
    }
}

extern "C" void kernel_launch(void* const* d_in, const int* in_sizes, int n_in,
                              void* d_out, int out_size, void* d_ws, size_t ws_size,
                              hipStream_t stream) {
    const float* enc          = (const float*)d_in[0];
    const int*   char_sizes   = (const int*)d_in[1];
    const int*   label_is_sep = (const int*)d_in[2];
    const int*   label_pos_id = (const int*)d_in[3];
    const float* posEmb       = (const float*)d_in[4];
    const float* W_ih         = (const float*)d_in[5];
    const float* W_hh         = (const float*)d_in[6];
    const float* b_ih         = (const float*)d_in[7];
    const float* b_hh         = (const float*)d_in[8];
    const float* W_lin        = (const float*)d_in[9];
    const float* b_lin        = (const float*)d_in[10];
    const float* W_cmb        = (const float*)d_in[11];
    const float* b_cmb        = (const float*)d_in[12];
    float* out = (float*)d_out;
    float* ws  = (float*)d_ws;

    hipLaunchKernelGGL(k_prep, dim3(2048), dim3(256), 0, stream,
                       W_ih, W_hh, W_cmb, posEmb, ws);
    hipLaunchKernelGGL(k_encw, dim3((NB * NT * NL + 255) / 256), dim3(256), 0, stream,
                       enc, W_lin, ws + OFF_ENCW);
    hipLaunchKernelGGL(k_init, dim3(1), dim3(384), 0, stream,
                       b_ih, b_hh, W_lin, b_lin, ws + OFF_ST);
    hipLaunchKernelGGL(k_fill, dim3((NB * NT * NL + 255) / 256), dim3(256), 0, stream, out);
    hipLaunchKernelGGL(k_seq, dim3(NB), dim3(1024), 0, stream,
                       enc, char_sizes, label_is_sep, label_pos_id,
                       b_ih, b_hh, W_lin, b_lin, b_cmb, ws, out);
}

// Round 4
// 48682.166 us; speedup vs baseline: 2.6840x; 2.6840x over previous
//
#include <hip/hip_runtime.h>
#include <math.h>

// ---------------------------------------------------------------------------
// Decoder_21371757265153 — single-block-per-sequence sequential decoder, v4.
// Same proven structure as round 1 (PASSED, 130 ms), with the event mat-vec
// rebuilt for memory-level parallelism: the 4.7 MB LSTM weight stream per
// event now uses all 1024 threads (8 K-slices x 128 row-groups), 12 float4
// loads in flight per thread per unrolled step, LDS partial reduction.
// Round-1 counters showed 4.7 GB/s/CU (latency-bound, ~1-2 loads in flight);
// this targets 100-250 GB/s/CU from the L3-resident weights.
// No cross-block communication of any kind.
// ---------------------------------------------------------------------------

namespace {
constexpr int NB = 16;
constexpr int NT = 1024;
constexpr int NE = 768;
constexpr int NH = 384;
constexpr int NG = 1536;
constexpr int NL = 33;

constexpr size_t OFF_WT    = 0;                         // WT[k][r]  (768x1536)
constexpr size_t N_WT      = (size_t)NE * NG;           // 1179648
constexpr size_t OFF_WAVGT = OFF_WT + N_WT;             // WavgT[k][j] (768x384)
constexpr size_t N_WAVGT   = (size_t)NE * NH;           // 294912
constexpr size_t OFF_PEW   = OFF_WAVGT + N_WAVGT;       // posEmbW[32][384]
constexpr size_t N_PEW     = 32 * NH;                   // 12288
constexpr size_t OFF_ENCW  = OFF_PEW + N_PEW;           // encW[16][1024][33]
constexpr size_t N_ENCW    = (size_t)NB * NT * NL;      // 540672
constexpr size_t OFF_ST    = OFF_ENCW + N_ENCW;         // h0[384] c0[384] hW0[33]
constexpr size_t OFF_BS    = OFF_ST + 1024;             // bsum[1536] = b_ih+b_hh
}

__device__ __forceinline__ float sigmf(float x) { return 1.0f / (1.0f + expf(-x)); }

__device__ __forceinline__ void fma4(float4& a, const float4 w, const float x) {
    a.x += w.x * x; a.y += w.y * x; a.z += w.z * x; a.w += w.w * x;
}

// ---- Build WT [768][1536], WavgT [768][384], posEmbW [32][384] ------------
__global__ void k_prep(const float* __restrict__ W_ih, const float* __restrict__ W_hh,
                       const float* __restrict__ W_cmb, const float* __restrict__ posEmb,
                       float* __restrict__ ws) {
    float* WT      = ws + OFF_WT;
    float* WavgT   = ws + OFF_WAVGT;
    float* posEmbW = ws + OFF_PEW;
    const int n1 = (int)N_WT, n2 = (int)N_WAVGT, n3 = (int)N_PEW;
    for (int i = blockIdx.x * blockDim.x + threadIdx.x; i < n1 + n2 + n3;
         i += gridDim.x * blockDim.x) {
        if (i < n1) {
            int k = i / NG, r = i % NG;
            WT[i] = (k < NH) ? W_ih[(size_t)r * NH + k] : W_hh[(size_t)r * NH + (k - NH)];
        } else if (i < n1 + n2) {
            int j2 = i - n1;
            int k = j2 / NH, j = j2 % NH;
            WavgT[j2] = W_cmb[(size_t)j * 896 + 128 + k];
        } else {
            int j3 = i - n1 - n2;
            int p = j3 / NH, j = j3 % NH;
            const float* pe = posEmb + p * 128;
            const float* wr = W_cmb + (size_t)j * 896;
            float a = 0.f;
            #pragma unroll 4
            for (int k = 0; k < 128; ++k) a += pe[k] * wr[k];
            posEmbW[j3] = a;
        }
    }
}

// ---- encW[bt][l] = enc[bt,:] @ W_lin[l, 384:] -----------------------------
__global__ void k_encw(const float* __restrict__ enc, const float* __restrict__ W_lin,
                       float* __restrict__ ws) {
    float* encW = ws + OFF_ENCW;
    int gid = blockIdx.x * 256 + threadIdx.x;
    if (gid >= NB * NT * NL) return;
    int bt = gid / NL, l = gid % NL;
    const float4* e4 = reinterpret_cast<const float4*>(enc + (size_t)bt * NE);
    const float4* w4 = reinterpret_cast<const float4*>(W_lin + (size_t)l * 1152 + NH);
    float a0 = 0, a1 = 0, a2 = 0, a3 = 0;
    for (int k = 0; k < NE / 4; ++k) {
        float4 e = e4[k], w = w4[k];
        a0 += e.x * w.x; a1 += e.y * w.y; a2 += e.z * w.z; a3 += e.w * w.w;
    }
    encW[gid] = (a0 + a1) + (a2 + a3);
}

// ---- h0/c0/hW0 + bsum ------------------------------------------------------
__global__ void k_init(const float* __restrict__ b_ih, const float* __restrict__ b_hh,
                       const float* __restrict__ W_lin, const float* __restrict__ b_lin,
                       float* __restrict__ ws) {
    __shared__ float shh[NH];
    int tid = threadIdx.x;
    float* st = ws + OFF_ST;
    float* bs = ws + OFF_BS;
    if (tid < NH) {
        float gi = b_ih[tid] + b_hh[tid];
        float gg = b_ih[2 * NH + tid] + b_hh[2 * NH + tid];
        float go = b_ih[3 * NH + tid] + b_hh[3 * NH + tid];
        float c = sigmf(gi) * tanhf(gg);
        float h = sigmf(go) * tanhf(c);
        st[tid] = h; st[NH + tid] = c; shh[tid] = h;
    }
    __syncthreads();
    if (tid < NL) {
        float a = b_lin[tid];
        for (int k = 0; k < NH; ++k) a += W_lin[(size_t)tid * 1152 + k] * shh[k];
        st[2 * NH + tid] = a;
    }
    for (int i = tid; i < NG; i += 1024) bs[i] = b_ih[i] + b_hh[i];
}

// ---- zero output (invalid rows stay zero => log_softmax = -log 33) --------
__global__ void k_fill(float* __restrict__ out) {
    int i = blockIdx.x * 256 + threadIdx.x;
    if (i < NB * NT * NL) out[i] = 0.f;
}

// ---- sequential decoder: 16 blocks, 1024 threads, no cross-block comm -----
__global__ __launch_bounds__(1024) void k_seq(
    const float* __restrict__ enc, const int* __restrict__ char_sizes,
    const int* __restrict__ label_is_sep, const int* __restrict__ label_pos_id,
    const float* __restrict__ W_lin, const float* __restrict__ b_lin,
    const float* __restrict__ b_cmb, const float* __restrict__ ws,
    float* __restrict__ out) {

    const float* WT    = ws + OFF_WT;
    const float* WavgT = ws + OFF_WAVGT;
    const float* pew   = ws + OFF_PEW;
    const float* encW  = ws + OFF_ENCW;
    const float* st0   = ws + OFF_ST;
    const float* bsum  = ws + OFF_BS;

    __shared__ float sh_Wlin[NL * NH];      // 50688 B
    __shared__ float sh_gp[8 * NG];         // 49152 B  (8 K-slice partials of g)
    __shared__ float sh_lp[8 * NH];         // 12288 B  (8 K-slice partials of lwp)
    __shared__ float sh_avg[NE];
    __shared__ float sh_xcat[NE];
    __shared__ float sh_h[NH], sh_lpeW[NH];
    __shared__ float sh_red[528];
    __shared__ float sh_hWb[64];
    __shared__ int sh_issep[NL], sh_posid[NL];

    const int b = blockIdx.x;
    const int tid = threadIdx.x;
    const int lane = tid & 63;
    const int wave = tid >> 6;
    int size = char_sizes[b];
    if (size > NT) size = NT;

    if (tid < NH) { sh_h[tid] = st0[tid]; sh_lpeW[tid] = 0.f; }
    float c_reg = (tid < NH) ? st0[NH + tid] : 0.f;
    if (tid < 64) sh_hWb[tid] = (tid < NL) ? st0[2 * NH + tid] : 0.f;
    if (tid < NL) { sh_issep[tid] = label_is_sep[tid]; sh_posid[tid] = label_pos_id[tid]; }
    for (int i = tid; i < NL * NH; i += 1024) {
        int l = i / NH, k = i - l * NH;
        sh_Wlin[i] = W_lin[(size_t)l * 1152 + k];
    }
    __syncthreads();

    int wlen = 0, nw = 0, npos = 0, plast = 0, lpe_pend = -1;
    const float* eWb = encW + (size_t)b * NT * NL;
    float* outb = out + (size_t)b * NT * NL;
    float e_cur = (lane < NL) ? eWb[lane] : 0.f;

    for (int t = 0; t < size; ++t) {
        // ---- logits + argmax (redundant per wave; shuffles full-wave) ----
        float e_nxt = (lane < NL && t + 1 < size) ? eWb[(size_t)(t + 1) * NL + lane] : 0.f;
        float ot = (lane < NL) ? tanhf(e_cur + sh_hWb[lane]) : -INFINITY;
        float bv = ot; int bi = lane;
        #pragma unroll
        for (int d = 32; d; d >>= 1) {
            float ov = __shfl_xor(bv, d);
            int   oi = __shfl_xor(bi, d);
            if (ov > bv || (ov == bv && oi < bi)) { bv = ov; bi = oi; }
        }
        const int aid = bi;
        if (wave == 0 && lane < NL) outb[(size_t)t * NL + lane] = ot;  // raw logits
        e_cur = e_nxt;

        // ---- scalar state update (uniform across all 1024 threads) ----
        const int issep = sh_issep[aid];
        const int wl_prev = wlen;
        int nw_new;
        if (issep) { npos += 1; nw_new = nw + 1; }
        else       { nw_new = (nw < 1) ? 1 : nw; }
        const int do_l = issep && (nw_new >= 2);
        if (issep && npos >= 2) lpe_pend = plast;
        if (issep) plast = sh_posid[aid];
        wlen = issep ? 1 : wlen + 1;
        nw = nw_new;

        if (do_l) {
            // ================== LSTM event ==================
            int start = t - wl_prev; if (start < 0) start = 0;
            const float denom = (float)((wl_prev < 1) ? 1 : wl_prev);

            // phase 1: window avg over enc[start..t); lazy lpeW refresh
            if (tid < NE) {
                float a = 0.f;
                const float* ep = enc + ((size_t)(b * NT + start)) * NE + tid;
                for (int r = start; r < t; ++r) { a += *ep; ep += NE; }
                sh_avg[tid] = a / denom;
            } else if (lpe_pend >= 0) {
                for (int j = tid - NE; j < NH; j += 256)
                    sh_lpeW[j] = pew[lpe_pend * NH + j];
            }
            __syncthreads();                                    // A0

            // phase 2: lwp partials — 8 K-slices x 96 j-groups (768 thr)
            if (tid < NE) {
                const int ks = tid / 96;        // 0..7 -> k in [96ks, 96ks+96)
                const int jg = tid % 96;        // j4 = jg*4
                const float* wp = WavgT + (size_t)(ks * 96) * NH + jg * 4;
                const float* xp = sh_avg + ks * 96;
                float4 acc = {0.f, 0.f, 0.f, 0.f};
                for (int k = 0; k < 96; k += 8) {
                    float4 w0 = *(const float4*)(wp);
                    float4 w1 = *(const float4*)(wp + NH);
                    float4 w2 = *(const float4*)(wp + 2 * NH);
                    float4 w3 = *(const float4*)(wp + 3 * NH);
                    float4 w4 = *(const float4*)(wp + 4 * NH);
                    float4 w5 = *(const float4*)(wp + 5 * NH);
                    float4 w6 = *(const float4*)(wp + 6 * NH);
                    float4 w7 = *(const float4*)(wp + 7 * NH);
                    wp += 8 * NH;
                    fma4(acc, w0, xp[k]);     fma4(acc, w1, xp[k + 1]);
                    fma4(acc, w2, xp[k + 2]); fma4(acc, w3, xp[k + 3]);
                    fma4(acc, w4, xp[k + 4]); fma4(acc, w5, xp[k + 5]);
                    fma4(acc, w6, xp[k + 6]); fma4(acc, w7, xp[k + 7]);
                }
                *(float4*)&sh_lp[ks * NH + jg * 4] = acc;
            }
            __syncthreads();                                    // A1

            // phase 2b: combine lwp partials -> xcat = [lwp, h]
            if (tid < NH) {
                float a = sh_lp[tid];
                #pragma unroll
                for (int ks = 1; ks < 8; ++ks) a += sh_lp[ks * NH + tid];
                sh_xcat[tid]      = tanhf(sh_lpeW[tid] + a + b_cmb[tid]);
                sh_xcat[NH + tid] = sh_h[tid];
            }
            __syncthreads();                                    // A2

            // phase 3: g partials — 8 K-slices x 128 row-groups (1024 thr)
            {
                const int ks = tid >> 7;          // 0..7
                const int rg = (tid & 127) * 4;   // 0..508
                const float* xp = sh_xcat + ks * 96;
                const float* wp = WT + (size_t)(ks * 96) * NG + rg;
                float4 a0 = {0.f, 0.f, 0.f, 0.f}, a1 = a0, a2 = a0;
                for (int k = 0; k < 96; k += 4) {
                    float4 w00 = *(const float4*)(wp);
                    float4 w01 = *(const float4*)(wp + 512);
                    float4 w02 = *(const float4*)(wp + 1024);
                    float4 w10 = *(const float4*)(wp + NG);
                    float4 w11 = *(const float4*)(wp + NG + 512);
                    float4 w12 = *(const float4*)(wp + NG + 1024);
                    float4 w20 = *(const float4*)(wp + 2 * NG);
                    float4 w21 = *(const float4*)(wp + 2 * NG + 512);
                    float4 w22 = *(const float4*)(wp + 2 * NG + 1024);
                    float4 w30 = *(const float4*)(wp + 3 * NG);
                    float4 w31 = *(const float4*)(wp + 3 * NG + 512);
                    float4 w32 = *(const float4*)(wp + 3 * NG + 1024);
                    wp += 4 * NG;
                    const float x0 = xp[k], x1 = xp[k + 1], x2 = xp[k + 2], x3 = xp[k + 3];
                    fma4(a0, w00, x0); fma4(a1, w01, x0); fma4(a2, w02, x0);
                    fma4(a0, w10, x1); fma4(a1, w11, x1); fma4(a2, w12, x1);
                    fma4(a0, w20, x2); fma4(a1, w21, x2); fma4(a2, w22, x2);
                    fma4(a0, w30, x3); fma4(a1, w31, x3); fma4(a2, w32, x3);
                }
                float* gp = sh_gp + ks * NG;
                *(float4*)&gp[rg]        = a0;
                *(float4*)&gp[512 + rg]  = a1;
                *(float4*)&gp[1024 + rg] = a2;
            }
            __syncthreads();                                    // B

            // phase 4: reduce partials, gates, commit h (c in register)
            if (tid < NH) {
                float g0 = bsum[tid],          g1 = bsum[NH + tid];
                float g2 = bsum[2 * NH + tid], g3 = bsum[3 * NH + tid];
                #pragma unroll
                for (int ks = 0; ks < 8; ++ks) {
                    const float* gp = sh_gp + ks * NG;
                    g0 += gp[tid];          g1 += gp[NH + tid];
                    g2 += gp[2 * NH + tid]; g3 += gp[3 * NH + tid];
                }
                float c2 = sigmf(g1) * c_reg + sigmf(g0) * tanhf(g2);
                float h2 = sigmf(g3) * tanhf(c2);
                c_reg = c2; sh_h[tid] = h2;
            }
            __syncthreads();                                    // C

            // phase 5: hWb = b_lin + W_lin[:, :384] @ h  (from LDS W_lin)
            if (tid < 528) {
                const int l = tid >> 4, p = tid & 15;
                const float* wr = sh_Wlin + l * NH + p * 24;
                const float* hp = sh_h + p * 24;
                float a = 0.f;
                #pragma unroll
                for (int k = 0; k < 24; ++k) a += wr[k] * hp[k];
                sh_red[tid] = a;
            }
            __syncthreads();                                    // D
            if (tid < NL) {
                float q = b_lin[tid];
                #pragma unroll
                for (int p = 0; p < 16; ++p) q += sh_red[tid * 16 + p];
                sh_hWb[tid] = q;
            }
            lpe_pend = -1;
            __syncthreads();                                    // E
        }
    }
}

// ---- parallel log-softmax over all 16384 rows -----------------------------
__global__ void k_post(float* __restrict__ out) {
    int row = blockIdx.x * 4 + (threadIdx.x >> 6);
    int lane = threadIdx.x & 63;
    if (row >= NB * NT) return;
    float* p = out + (size_t)row * NL;
    float x = (lane < NL) ? p[lane] : -INFINITY;
    float m = x;
    #pragma unroll
    for (int d = 32; d; d >>= 1) m = fmaxf(m, __shfl_xor(m, d));
    float e = (lane < NL) ? expf(x - m) : 0.f;
    float su = e;
    #pragma unroll
    for (int d = 32; d; d >>= 1) su += __shfl_xor(su, d);
    if (lane < NL) p[lane] = (x - m) - logf(su);
}

extern "C" void kernel_launch(void* const* d_in, const int* in_sizes, int n_in,
                              void* d_out, int out_size, void* d_ws, size_t ws_size,
                              hipStream_t stream) {
    const float* enc          = (const float*)d_in[0];
    const int*   char_sizes   = (const int*)d_in[1];
    const int*   label_is_sep = (const int*)d_in[2];
    const int*   label_pos_id = (const int*)d_in[3];
    const float* posEmb       = (const float*)d_in[4];
    const float* W_ih         = (const float*)d_in[5];
    const float* W_hh         = (const float*)d_in[6];
    const float* b_ih         = (const float*)d_in[7];
    const float* b_hh         = (const float*)d_in[8];
    const float* W_lin        = (const float*)d_in[9];
    const float* b_lin        = (const float*)d_in[10];
    const float* W_cmb        = (const float*)d_in[11];
    const float* b_cmb        = (const float*)d_in[12];
    float* out = (float*)d_out;
    float* ws  = (float*)d_ws;

    hipLaunchKernelGGL(k_prep, dim3(2048), dim3(256), 0, stream,
                       W_ih, W_hh, W_cmb, posEmb, ws);
    hipLaunchKernelGGL(k_encw, dim3((NB * NT * NL + 255) / 256), dim3(256), 0, stream,
                       enc, W_lin, ws);
    hipLaunchKernelGGL(k_init, dim3(1), dim3(1024), 0, stream,
                       b_ih, b_hh, W_lin, b_lin, ws);
    hipLaunchKernelGGL(k_fill, dim3((NB * NT * NL + 255) / 256), dim3(256), 0, stream, out);
    hipLaunchKernelGGL(k_seq, dim3(NB), dim3(1024), 0, stream,
                       enc, char_sizes, label_is_sep, label_pos_id,
                       W_lin, b_lin, b_cmb, ws, out);
    hipLaunchKernelGGL(k_post, dim3((NB * NT + 3) / 4), dim3(256), 0, stream, out);
}

// Round 5
// 25343.211 us; speedup vs baseline: 5.1557x; 1.9209x over previous
//
#include <hip/hip_runtime.h>
#include <math.h>

// ---------------------------------------------------------------------------
// Decoder_21371757265153 — single-block-per-sequence sequential decoder, v5.
// vs v4 (PASSED, 48.7 ms):
//  - __launch_bounds__(1024, 4): 1 block/CU -> 128 VGPR budget (v4 got 64,
//    which strangled memory-level parallelism in the weight stream).
//  - phase 3 WT stream: explicit 2-deep register prefetch pipeline
//    (6 float4 in flight/thread, ~96 KB/CU) for the 4.7 MB/event stream.
//  - lwp matvec eliminated: pc = exclusive-prefix of enc @ W_cmb[:,128:].T
//    precomputed (25 MB, guarded by ws_size; falls back to v4 path).
// ---------------------------------------------------------------------------

namespace {
constexpr int NB = 16;
constexpr int NT = 1024;
constexpr int NE = 768;
constexpr int NH = 384;
constexpr int NG = 1536;
constexpr int NL = 33;

constexpr size_t OFF_WT    = 0;                         // WT[k][r]  (768x1536)
constexpr size_t N_WT      = (size_t)NE * NG;           // 1179648
constexpr size_t OFF_WAVGT = OFF_WT + N_WT;             // WavgT[k][j] (768x384)
constexpr size_t N_WAVGT   = (size_t)NE * NH;           // 294912
constexpr size_t OFF_PEW   = OFF_WAVGT + N_WAVGT;       // posEmbW[32][384]
constexpr size_t N_PEW     = 32 * NH;                   // 12288
constexpr size_t OFF_ENCW  = OFF_PEW + N_PEW;           // encW[16][1024][33]
constexpr size_t N_ENCW    = (size_t)NB * NT * NL;      // 540672
constexpr size_t OFF_ST    = OFF_ENCW + N_ENCW;         // h0[384] c0[384] hW0[33]
constexpr size_t OFF_BS    = OFF_ST + 1024;             // bsum[1536]
constexpr size_t OFF_PC    = OFF_BS + 2048;             // pc[16][1025][384]
constexpr size_t N_PC      = (size_t)NB * 1025 * NH;    // 6297600
}

__device__ __forceinline__ float sigmf(float x) { return 1.0f / (1.0f + expf(-x)); }

__device__ __forceinline__ void fma4(float4& a, const float4 w, const float x) {
    a.x += w.x * x; a.y += w.y * x; a.z += w.z * x; a.w += w.w * x;
}

// ---- Build WT [768][1536], WavgT [768][384], posEmbW [32][384] ------------
__global__ void k_prep(const float* __restrict__ W_ih, const float* __restrict__ W_hh,
                       const float* __restrict__ W_cmb, const float* __restrict__ posEmb,
                       float* __restrict__ ws) {
    float* WT      = ws + OFF_WT;
    float* WavgT   = ws + OFF_WAVGT;
    float* posEmbW = ws + OFF_PEW;
    const int n1 = (int)N_WT, n2 = (int)N_WAVGT, n3 = (int)N_PEW;
    for (int i = blockIdx.x * blockDim.x + threadIdx.x; i < n1 + n2 + n3;
         i += gridDim.x * blockDim.x) {
        if (i < n1) {
            int k = i / NG, r = i % NG;
            WT[i] = (k < NH) ? W_ih[(size_t)r * NH + k] : W_hh[(size_t)r * NH + (k - NH)];
        } else if (i < n1 + n2) {
            int j2 = i - n1;
            int k = j2 / NH, j = j2 % NH;
            WavgT[j2] = W_cmb[(size_t)j * 896 + 128 + k];
        } else {
            int j3 = i - n1 - n2;
            int p = j3 / NH, j = j3 % NH;
            const float* pe = posEmb + p * 128;
            const float* wr = W_cmb + (size_t)j * 896;
            float a = 0.f;
            #pragma unroll 4
            for (int k = 0; k < 128; ++k) a += pe[k] * wr[k];
            posEmbW[j3] = a;
        }
    }
}

// ---- encW[bt][l] = enc[bt,:] @ W_lin[l, 384:] -----------------------------
__global__ void k_encw(const float* __restrict__ enc, const float* __restrict__ W_lin,
                       float* __restrict__ ws) {
    float* encW = ws + OFF_ENCW;
    int gid = blockIdx.x * 256 + threadIdx.x;
    if (gid >= NB * NT * NL) return;
    int bt = gid / NL, l = gid % NL;
    const float4* e4 = reinterpret_cast<const float4*>(enc + (size_t)bt * NE);
    const float4* w4 = reinterpret_cast<const float4*>(W_lin + (size_t)l * 1152 + NH);
    float a0 = 0, a1 = 0, a2 = 0, a3 = 0;
    for (int k = 0; k < NE / 4; ++k) {
        float4 e = e4[k], w = w4[k];
        a0 += e.x * w.x; a1 += e.y * w.y; a2 += e.z * w.z; a3 += e.w * w.w;
    }
    encW[gid] = (a0 + a1) + (a2 + a3);
}

// ---- pc[b][t][j] = enc[b,t,:] @ W_cmb[j,128:]  (pre-prefix) ---------------
__global__ void k_encCmb(const float* __restrict__ enc, const float* __restrict__ W_cmb,
                         float* __restrict__ ws) {
    __shared__ float tile[16][NE];
    float* pc = ws + OFF_PC;
    int blk = blockIdx.x;          // 1024 blocks = 16 seq x 64 chunks
    int b = blk >> 6;
    int t0 = (blk & 63) * 16;
    for (int i = threadIdx.x; i < 16 * NE; i += 384) {
        int row = i / NE, k = i % NE;
        tile[row][k] = enc[((size_t)(b * NT + t0 + row)) * NE + k];
    }
    __syncthreads();
    int j = threadIdx.x;           // 384 threads
    const float4* w4 = (const float4*)(W_cmb + (size_t)j * 896 + 128);
    float acc[16];
    #pragma unroll
    for (int r = 0; r < 16; ++r) acc[r] = 0.f;
    for (int q = 0; q < NE / 4; ++q) {
        float4 w = w4[q];
        #pragma unroll
        for (int r = 0; r < 16; ++r) {
            acc[r] += w.x * tile[r][q * 4] + w.y * tile[r][q * 4 + 1]
                    + w.z * tile[r][q * 4 + 2] + w.w * tile[r][q * 4 + 3];
        }
    }
    #pragma unroll
    for (int r = 0; r < 16; ++r)
        pc[((size_t)b * 1025 + t0 + r) * NH + j] = acc[r];
}

// ---- in-place exclusive prefix over t per (b,j) ---------------------------
__global__ void k_prefix(float* __restrict__ ws) {
    float* pc = ws + OFF_PC;
    int id = blockIdx.x * 256 + threadIdx.x;
    if (id >= NB * NH) return;
    int b = id / NH, j = id % NH;
    float* p = pc + ((size_t)b * 1025) * NH + j;
    float s = 0.f;
    for (int t = 0; t < NT; ++t) {
        float x = p[(size_t)t * NH];
        p[(size_t)t * NH] = s;
        s += x;
    }
    p[(size_t)NT * NH] = s;
}

// ---- h0/c0/hW0 + bsum ------------------------------------------------------
__global__ void k_init(const float* __restrict__ b_ih, const float* __restrict__ b_hh,
                       const float* __restrict__ W_lin, const float* __restrict__ b_lin,
                       float* __restrict__ ws) {
    __shared__ float shh[NH];
    int tid = threadIdx.x;
    float* st = ws + OFF_ST;
    float* bs = ws + OFF_BS;
    if (tid < NH) {
        float gi = b_ih[tid] + b_hh[tid];
        float gg = b_ih[2 * NH + tid] + b_hh[2 * NH + tid];
        float go = b_ih[3 * NH + tid] + b_hh[3 * NH + tid];
        float c = sigmf(gi) * tanhf(gg);
        float h = sigmf(go) * tanhf(c);
        st[tid] = h; st[NH + tid] = c; shh[tid] = h;
    }
    __syncthreads();
    if (tid < NL) {
        float a = b_lin[tid];
        for (int k = 0; k < NH; ++k) a += W_lin[(size_t)tid * 1152 + k] * shh[k];
        st[2 * NH + tid] = a;
    }
    for (int i = tid; i < NG; i += 1024) bs[i] = b_ih[i] + b_hh[i];
}

// ---- zero output (invalid rows stay zero => log_softmax = -log 33) --------
__global__ void k_fill(float* __restrict__ out) {
    int i = blockIdx.x * 256 + threadIdx.x;
    if (i < NB * NT * NL) out[i] = 0.f;
}

// ---- sequential decoder: 16 blocks, 1024 threads, 1 block/CU --------------
__global__ __launch_bounds__(1024, 4) void k_seq(
    const float* __restrict__ enc, const int* __restrict__ char_sizes,
    const int* __restrict__ label_is_sep, const int* __restrict__ label_pos_id,
    const float* __restrict__ W_lin, const float* __restrict__ b_lin,
    const float* __restrict__ b_cmb, const float* __restrict__ ws,
    float* __restrict__ out, const int use_pc) {

    const float* WT    = ws + OFF_WT;
    const float* WavgT = ws + OFF_WAVGT;
    const float* pew   = ws + OFF_PEW;
    const float* encW  = ws + OFF_ENCW;
    const float* st0   = ws + OFF_ST;
    const float* bsum  = ws + OFF_BS;
    const float* pc    = ws + OFF_PC;

    __shared__ float sh_Wlin[NL * NH];      // 50688 B
    __shared__ float sh_gp[8 * NG];         // 49152 B
    __shared__ float sh_lp[8 * NH];         // 12288 B (fallback path)
    __shared__ float sh_avg[NE];
    __shared__ float sh_xcat[NE];
    __shared__ float sh_h[NH], sh_lpeW[NH];
    __shared__ float sh_red[528];
    __shared__ float sh_hWb[64];
    __shared__ int sh_issep[NL], sh_posid[NL];

    const int b = blockIdx.x;
    const int tid = threadIdx.x;
    const int lane = tid & 63;
    const int wave = tid >> 6;
    int size = char_sizes[b];
    if (size > NT) size = NT;

    if (tid < NH) { sh_h[tid] = st0[tid]; sh_lpeW[tid] = 0.f; }
    float c_reg = (tid < NH) ? st0[NH + tid] : 0.f;
    if (tid < 64) sh_hWb[tid] = (tid < NL) ? st0[2 * NH + tid] : 0.f;
    if (tid < NL) { sh_issep[tid] = label_is_sep[tid]; sh_posid[tid] = label_pos_id[tid]; }
    for (int i = tid; i < NL * NH; i += 1024) {
        int l = i / NH, k = i - l * NH;
        sh_Wlin[i] = W_lin[(size_t)l * 1152 + k];
    }
    __syncthreads();

    int wlen = 0, nw = 0, npos = 0, plast = 0, lpe_pend = -1;
    const float* eWb = encW + (size_t)b * NT * NL;
    const float* pcb = pc + ((size_t)b * 1025) * NH;
    float* outb = out + (size_t)b * NT * NL;
    float e_cur = (lane < NL) ? eWb[lane] : 0.f;

    for (int t = 0; t < size; ++t) {
        // ---- logits + argmax (redundant per wave) ----
        float e_nxt = (lane < NL && t + 1 < size) ? eWb[(size_t)(t + 1) * NL + lane] : 0.f;
        float ot = (lane < NL) ? tanhf(e_cur + sh_hWb[lane]) : -INFINITY;
        float bv = ot; int bi = lane;
        #pragma unroll
        for (int d = 32; d; d >>= 1) {
            float ov = __shfl_xor(bv, d);
            int   oi = __shfl_xor(bi, d);
            if (ov > bv || (ov == bv && oi < bi)) { bv = ov; bi = oi; }
        }
        const int aid = bi;
        if (wave == 0 && lane < NL) outb[(size_t)t * NL + lane] = ot;  // raw logits
        e_cur = e_nxt;

        // ---- scalar state update (uniform) ----
        const int issep = sh_issep[aid];
        const int wl_prev = wlen;
        int nw_new;
        if (issep) { npos += 1; nw_new = nw + 1; }
        else       { nw_new = (nw < 1) ? 1 : nw; }
        const int do_l = issep && (nw_new >= 2);
        if (issep && npos >= 2) lpe_pend = plast;
        if (issep) plast = sh_posid[aid];
        wlen = issep ? 1 : wlen + 1;
        nw = nw_new;

        if (do_l) {
            // ================== LSTM event ==================
            int start = t - wl_prev; if (start < 0) start = 0;
            const float denom = (float)((wl_prev < 1) ? 1 : wl_prev);

            if (use_pc) {
                // phase A: lwp pre-activation from prefix gather; lpeW refresh
                if (tid < NH) {
                    sh_avg[tid] = (pcb[(size_t)t * NH + tid] - pcb[(size_t)start * NH + tid]) / denom;
                } else if (tid >= NE && lpe_pend >= 0) {
                    for (int j = tid - NE; j < NH; j += 256)
                        sh_lpeW[j] = pew[lpe_pend * NH + j];
                }
                __syncthreads();
                if (tid < NH) {
                    sh_xcat[tid]      = tanhf(sh_lpeW[tid] + sh_avg[tid] + b_cmb[tid]);
                    sh_xcat[NH + tid] = sh_h[tid];
                }
                __syncthreads();
            } else {
                // fallback (v4): window sum + WavgT matvec
                if (tid < NE) {
                    float a = 0.f;
                    const float* ep = enc + ((size_t)(b * NT + start)) * NE + tid;
                    for (int r = start; r < t; ++r) { a += *ep; ep += NE; }
                    sh_avg[tid] = a / denom;
                } else if (lpe_pend >= 0) {
                    for (int j = tid - NE; j < NH; j += 256)
                        sh_lpeW[j] = pew[lpe_pend * NH + j];
                }
                __syncthreads();
                if (tid < NE) {
                    const int ks = tid / 96, jg = tid % 96;
                    const float* wp = WavgT + (size_t)(ks * 96) * NH + jg * 4;
                    const float* xp = sh_avg + ks * 96;
                    float4 acc = {0.f, 0.f, 0.f, 0.f};
                    for (int k = 0; k < 96; k += 4) {
                        float4 w0 = *(const float4*)(wp);
                        float4 w1 = *(const float4*)(wp + NH);
                        float4 w2 = *(const float4*)(wp + 2 * NH);
                        float4 w3 = *(const float4*)(wp + 3 * NH);
                        wp += 4 * NH;
                        fma4(acc, w0, xp[k]);     fma4(acc, w1, xp[k + 1]);
                        fma4(acc, w2, xp[k + 2]); fma4(acc, w3, xp[k + 3]);
                    }
                    *(float4*)&sh_lp[ks * NH + jg * 4] = acc;
                }
                __syncthreads();
                if (tid < NH) {
                    float a = sh_lp[tid];
                    #pragma unroll
                    for (int ks = 1; ks < 8; ++ks) a += sh_lp[ks * NH + tid];
                    sh_xcat[tid]      = tanhf(sh_lpeW[tid] + a + b_cmb[tid]);
                    sh_xcat[NH + tid] = sh_h[tid];
                }
                __syncthreads();
            }

            // phase 3: g partials — 8 K-slices x 128 row-groups, 2-deep pipeline
            {
                const int ks = tid >> 7;          // 0..7
                const int rg = (tid & 127) * 4;   // 0..508
                const float* xp = sh_xcat + ks * 96;
                const float* wp = WT + (size_t)(ks * 96) * NG + rg;
                float4 a0 = {0.f, 0.f, 0.f, 0.f}, a1 = a0, a2 = a0;
                float4 c00 = *(const float4*)(wp);
                float4 c01 = *(const float4*)(wp + 512);
                float4 c02 = *(const float4*)(wp + 1024);
                float4 c10 = *(const float4*)(wp + NG);
                float4 c11 = *(const float4*)(wp + NG + 512);
                float4 c12 = *(const float4*)(wp + NG + 1024);
                wp += 2 * NG;
                #pragma unroll 1
                for (int k = 0; k < 94; k += 2) {
                    float4 n00 = *(const float4*)(wp);
                    float4 n01 = *(const float4*)(wp + 512);
                    float4 n02 = *(const float4*)(wp + 1024);
                    float4 n10 = *(const float4*)(wp + NG);
                    float4 n11 = *(const float4*)(wp + NG + 512);
                    float4 n12 = *(const float4*)(wp + NG + 1024);
                    wp += 2 * NG;
                    const float x0 = xp[k], x1 = xp[k + 1];
                    fma4(a0, c00, x0); fma4(a1, c01, x0); fma4(a2, c02, x0);
                    fma4(a0, c10, x1); fma4(a1, c11, x1); fma4(a2, c12, x1);
                    c00 = n00; c01 = n01; c02 = n02;
                    c10 = n10; c11 = n11; c12 = n12;
                }
                {
                    const float x0 = xp[94], x1 = xp[95];
                    fma4(a0, c00, x0); fma4(a1, c01, x0); fma4(a2, c02, x0);
                    fma4(a0, c10, x1); fma4(a1, c11, x1); fma4(a2, c12, x1);
                }
                float* gp = sh_gp + ks * NG;
                *(float4*)&gp[rg]        = a0;
                *(float4*)&gp[512 + rg]  = a1;
                *(float4*)&gp[1024 + rg] = a2;
            }
            __syncthreads();                                    // B

            // phase 4: reduce partials, gates, commit h (c in register)
            if (tid < NH) {
                float g0 = bsum[tid],          g1 = bsum[NH + tid];
                float g2 = bsum[2 * NH + tid], g3 = bsum[3 * NH + tid];
                #pragma unroll
                for (int ks = 0; ks < 8; ++ks) {
                    const float* gp = sh_gp + ks * NG;
                    g0 += gp[tid];          g1 += gp[NH + tid];
                    g2 += gp[2 * NH + tid]; g3 += gp[3 * NH + tid];
                }
                float c2 = sigmf(g1) * c_reg + sigmf(g0) * tanhf(g2);
                float h2 = sigmf(g3) * tanhf(c2);
                c_reg = c2; sh_h[tid] = h2;
            }
            __syncthreads();                                    // C

            // phase 5: hWb = b_lin + W_lin[:, :384] @ h  (LDS W_lin)
            if (tid < 528) {
                const int l = tid >> 4, p = tid & 15;
                const float* wr = sh_Wlin + l * NH + p * 24;
                const float* hp = sh_h + p * 24;
                float a = 0.f;
                #pragma unroll
                for (int k = 0; k < 24; ++k) a += wr[k] * hp[k];
                sh_red[tid] = a;
            }
            __syncthreads();                                    // D
            if (tid < NL) {
                float q = b_lin[tid];
                #pragma unroll
                for (int p = 0; p < 16; ++p) q += sh_red[tid * 16 + p];
                sh_hWb[tid] = q;
            }
            lpe_pend = -1;
            __syncthreads();                                    // E
        }
    }
}

// ---- parallel log-softmax over all 16384 rows -----------------------------
__global__ void k_post(float* __restrict__ out) {
    int row = blockIdx.x * 4 + (threadIdx.x >> 6);
    int lane = threadIdx.x & 63;
    if (row >= NB * NT) return;
    float* p = out + (size_t)row * NL;
    float x = (lane < NL) ? p[lane] : -INFINITY;
    float m = x;
    #pragma unroll
    for (int d = 32; d; d >>= 1) m = fmaxf(m, __shfl_xor(m, d));
    float e = (lane < NL) ? expf(x - m) : 0.f;
    float su = e;
    #pragma unroll
    for (int d = 32; d; d >>= 1) su += __shfl_xor(su, d);
    if (lane < NL) p[lane] = (x - m) - logf(su);
}

extern "C" void kernel_launch(void* const* d_in, const int* in_sizes, int n_in,
                              void* d_out, int out_size, void* d_ws, size_t ws_size,
                              hipStream_t stream) {
    const float* enc          = (const float*)d_in[0];
    const int*   char_sizes   = (const int*)d_in[1];
    const int*   label_is_sep = (const int*)d_in[2];
    const int*   label_pos_id = (const int*)d_in[3];
    const float* posEmb       = (const float*)d_in[4];
    const float* W_ih         = (const float*)d_in[5];
    const float* W_hh         = (const float*)d_in[6];
    const float* b_ih         = (const float*)d_in[7];
    const float* b_hh         = (const float*)d_in[8];
    const float* W_lin        = (const float*)d_in[9];
    const float* b_lin        = (const float*)d_in[10];
    const float* W_cmb        = (const float*)d_in[11];
    const float* b_cmb        = (const float*)d_in[12];
    float* out = (float*)d_out;
    float* ws  = (float*)d_ws;

    const size_t need_pc = (OFF_PC + N_PC) * sizeof(float);
    const int use_pc = (ws_size >= need_pc) ? 1 : 0;

    hipLaunchKernelGGL(k_prep, dim3(2048), dim3(256), 0, stream,
                       W_ih, W_hh, W_cmb, posEmb, ws);
    hipLaunchKernelGGL(k_encw, dim3((NB * NT * NL + 255) / 256), dim3(256), 0, stream,
                       enc, W_lin, ws);
    if (use_pc) {
        hipLaunchKernelGGL(k_encCmb, dim3(1024), dim3(384), 0, stream, enc, W_cmb, ws);
        hipLaunchKernelGGL(k_prefix, dim3((NB * NH + 255) / 256), dim3(256), 0, stream, ws);
    }
    hipLaunchKernelGGL(k_init, dim3(1), dim3(1024), 0, stream,
                       b_ih, b_hh, W_lin, b_lin, ws);
    hipLaunchKernelGGL(k_fill, dim3((NB * NT * NL + 255) / 256), dim3(256), 0, stream, out);
    hipLaunchKernelGGL(k_seq, dim3(NB), dim3(1024), 0, stream,
                       enc, char_sizes, label_is_sep, label_pos_id,
                       W_lin, b_lin, b_cmb, ws, out, use_pc);
    hipLaunchKernelGGL(k_post, dim3((NB * NT + 3) / 4), dim3(256), 0, stream, out);
}

// Round 7
// 11749.246 us; speedup vs baseline: 11.1209x; 2.1570x over previous
//
#include <hip/hip_runtime.h>
#include <math.h>

// ---------------------------------------------------------------------------
// Decoder_21371757265153 — v7: round-structured batched decoder.
// NO cross-block communication: the ONLY synchronization is kernel boundaries.
// Per round r (1024 rounds = worst-case event count):
//   kA (16 blocks, 1/sequence): apply gates from round r-1 (if pending),
//       scan to next event, emit xcat[768] + pending flag. Done seqs exit ~1us.
//   kB (48 blocks = 8 k-slices x 6 row-groups): batched matvec
//       g_partial[s][ks][1536] = WT_slice^T @ xcat[s] for ALL 16 sequences —
//       the 4.7 MB weight matrix is read ONCE per round (vs once per seq) and
//       stays L2-resident per XCD across rounds.
// Worst-case events = 1023 (sep at every t>=1) <= ROUNDS, so no fallback
// path exists or is needed. Finished rounds cost ~2 small null dispatches.
// ---------------------------------------------------------------------------

namespace {
constexpr int NB = 16;
constexpr int NT = 1024;
constexpr int NE = 768;
constexpr int NH = 384;
constexpr int NL = 33;
constexpr int ROUNDS = 1024;

constexpr size_t OFF_WT    = 0;                       // WT[k][1536], k<768
constexpr size_t N_WT      = (size_t)NE * 1536;       // 1179648
constexpr size_t OFF_PEW   = OFF_WT + N_WT;           // posEmbW[32][384]
constexpr size_t N_PEW     = 32 * NH;
constexpr size_t OFF_ENCW  = OFF_PEW + N_PEW;         // encW[16][1024][33]
constexpr size_t N_ENCW    = (size_t)NB * NT * NL;
constexpr size_t OFF_BS    = OFF_ENCW + N_ENCW;       // bsum[1536]
constexpr size_t OFF_PAD   = OFF_BS + 2048;           // reserved
constexpr size_t OFF_PC    = OFF_PAD + 1024;          // pc[16][1025][384]
constexpr size_t N_PC      = (size_t)NB * 1025 * NH;
constexpr size_t OFF_STATE = OFF_PC + N_PC;           // 16 x 2048
constexpr size_t ST_STRIDE = 2048;
constexpr size_t OFF_GP    = OFF_STATE + NB * ST_STRIDE;   // gpart[16][8][1536]
constexpr size_t OFF_FLG   = OFF_GP + (size_t)NB * 8 * 1536;
// end = 8,262,672 floats = 31.5 MiB  (< v5's proven-working 33.3 MB need)

// state block layout (per sequence): ints [0..15], floats after
constexpr int IX_T = 0, IX_WLEN = 1, IX_NW = 2, IX_NPOS = 3, IX_PLAST = 4,
              IX_LPEP = 5, IX_PEND = 6, IX_DONE = 7, IX_LPEE = 8;
constexpr int FX_HWB = 16;   // 33 floats
constexpr int FX_H   = 64;   // 384
constexpr int FX_C   = 448;  // 384
constexpr int FX_XC  = 832;  // 768
}

__device__ __forceinline__ float sigmf(float x) { return 1.0f / (1.0f + expf(-x)); }

// ---- WT[k][r] (k-major) + posEmbW -----------------------------------------
__global__ void k_prep(const float* __restrict__ W_ih, const float* __restrict__ W_hh,
                       const float* __restrict__ W_cmb, const float* __restrict__ posEmb,
                       float* __restrict__ ws) {
    float* WT = ws + OFF_WT;
    float* pw = ws + OFF_PEW;
    const int n1 = (int)N_WT, n2 = (int)N_PEW;
    for (int i = blockIdx.x * blockDim.x + threadIdx.x; i < n1 + n2;
         i += gridDim.x * blockDim.x) {
        if (i < n1) {
            int k = i / 1536, r = i % 1536;
            WT[i] = (k < NH) ? W_ih[(size_t)r * NH + k] : W_hh[(size_t)r * NH + (k - NH)];
        } else {
            int j3 = i - n1;
            int p = j3 / NH, j = j3 % NH;
            const float* pe = posEmb + p * 128;
            const float* wr = W_cmb + (size_t)j * 896;
            float a = 0.f;
            #pragma unroll 4
            for (int k = 0; k < 128; ++k) a += pe[k] * wr[k];
            pw[j3] = a;
        }
    }
}

// ---- encW[bt][l] = enc[bt,:] @ W_lin[l, 384:] -----------------------------
__global__ void k_encw(const float* __restrict__ enc, const float* __restrict__ W_lin,
                       float* __restrict__ ws) {
    float* encW = ws + OFF_ENCW;
    int gid = blockIdx.x * 256 + threadIdx.x;
    if (gid >= NB * NT * NL) return;
    int bt = gid / NL, l = gid % NL;
    const float4* e4 = (const float4*)(enc + (size_t)bt * NE);
    const float4* w4 = (const float4*)(W_lin + (size_t)l * 1152 + NH);
    float a0 = 0, a1 = 0, a2 = 0, a3 = 0;
    for (int k = 0; k < NE / 4; ++k) {
        float4 e = e4[k], w = w4[k];
        a0 += e.x * w.x; a1 += e.y * w.y; a2 += e.z * w.z; a3 += e.w * w.w;
    }
    encW[gid] = (a0 + a1) + (a2 + a3);
}

// ---- pc[b][t][j] = enc[b,t,:] @ W_cmb[j,128:]  (pre-prefix) ---------------
__global__ void k_encCmb(const float* __restrict__ enc, const float* __restrict__ W_cmb,
                         float* __restrict__ ws) {
    __shared__ float tile[16][NE];
    float* pc = ws + OFF_PC;
    int blk = blockIdx.x;
    int b = blk >> 6;
    int t0 = (blk & 63) * 16;
    for (int i = threadIdx.x; i < 16 * NE; i += 384) {
        int row = i / NE, k = i % NE;
        tile[row][k] = enc[((size_t)(b * NT + t0 + row)) * NE + k];
    }
    __syncthreads();
    int j = threadIdx.x;
    const float4* w4 = (const float4*)(W_cmb + (size_t)j * 896 + 128);
    float acc[16];
    #pragma unroll
    for (int r = 0; r < 16; ++r) acc[r] = 0.f;
    for (int q = 0; q < NE / 4; ++q) {
        float4 w = w4[q];
        #pragma unroll
        for (int r = 0; r < 16; ++r) {
            acc[r] += w.x * tile[r][q * 4] + w.y * tile[r][q * 4 + 1]
                    + w.z * tile[r][q * 4 + 2] + w.w * tile[r][q * 4 + 3];
        }
    }
    #pragma unroll
    for (int r = 0; r < 16; ++r)
        pc[((size_t)b * 1025 + t0 + r) * NH + j] = acc[r];
}

// ---- in-place exclusive prefix over t per (b,j) ---------------------------
__global__ void k_prefix(float* __restrict__ ws) {
    float* pc = ws + OFF_PC;
    int id = blockIdx.x * 256 + threadIdx.x;
    if (id >= NB * NH) return;
    int b = id / NH, j = id % NH;
    float* p = pc + ((size_t)b * 1025) * NH + j;
    float s = 0.f;
    for (int t = 0; t < NT; ++t) {
        float x = p[(size_t)t * NH];
        p[(size_t)t * NH] = s;
        s += x;
    }
    p[(size_t)NT * NH] = s;
}

// ---- init: h0/c0/hW0 into every state block, bsum, flags ------------------
__global__ void k_init(const float* __restrict__ b_ih, const float* __restrict__ b_hh,
                       const float* __restrict__ W_lin, const float* __restrict__ b_lin,
                       float* __restrict__ ws) {
    __shared__ float shh[NH], shc[NH], shw[NL];
    int tid = threadIdx.x;
    if (tid < NH) {
        float gi = b_ih[tid] + b_hh[tid];
        float gg = b_ih[2 * NH + tid] + b_hh[2 * NH + tid];
        float go = b_ih[3 * NH + tid] + b_hh[3 * NH + tid];
        float c = sigmf(gi) * tanhf(gg);
        float h = sigmf(go) * tanhf(c);
        shh[tid] = h; shc[tid] = c;
    }
    __syncthreads();
    if (tid < NL) {
        float a = b_lin[tid];
        for (int k = 0; k < NH; ++k) a += W_lin[(size_t)tid * 1152 + k] * shh[k];
        shw[tid] = a;
    }
    for (int i = tid; i < 4 * NH; i += 1024) ws[OFF_BS + i] = b_ih[i] + b_hh[i];
    __syncthreads();
    for (int s = 0; s < NB; ++s) {
        float* stf = ws + OFF_STATE + (size_t)s * ST_STRIDE;
        int* sti = (int*)stf;
        if (tid < 16) sti[tid] = (tid == IX_LPEP || tid == IX_LPEE) ? -1 : 0;
        if (tid < NH) { stf[FX_H + tid] = shh[tid]; stf[FX_C + tid] = shc[tid]; }
        if (tid < NL) stf[FX_HWB + tid] = shw[tid];
    }
    if (tid == 0) *(int*)(ws + OFF_FLG) = 0;
}

// ---- zero output (invalid rows stay zero => log_softmax = -log 33) --------
__global__ void k_fill(float* __restrict__ out) {
    int i = blockIdx.x * 256 + threadIdx.x;
    if (i < NB * NT * NL) out[i] = 0.f;
}

// ---- kA: per-sequence — apply gates, scan to next event, emit xcat --------
__global__ __launch_bounds__(512) void kA(
    const int* __restrict__ char_sizes,
    const int* __restrict__ label_is_sep, const int* __restrict__ label_pos_id,
    const float* __restrict__ W_lin, const float* __restrict__ b_lin,
    const float* __restrict__ b_cmb, float* __restrict__ ws,
    float* __restrict__ out) {

    const int s = blockIdx.x, tid = threadIdx.x;
    const int lane = tid & 63, wave = tid >> 6;
    float* stf = ws + OFF_STATE + (size_t)s * ST_STRIDE;
    int* sti = (int*)stf;
    if (sti[IX_DONE]) return;

    const float* encW = ws + OFF_ENCW;
    const float* pew  = ws + OFF_PEW;
    const float* bsum = ws + OFF_BS;
    const float* pcb  = ws + OFF_PC + (size_t)s * 1025 * NH;
    const float* gp   = ws + OFF_GP + (size_t)s * 8 * 1536;

    __shared__ float sh_h[NH], sh_hWb[NL], sh_red[264];
    __shared__ int sh_issep[NL], sh_posid[NL];

    const int pending = sti[IX_PEND];
    if (tid < NL) { sh_issep[tid] = label_is_sep[tid]; sh_posid[tid] = label_pos_id[tid]; }

    if (pending) {
        // apply gates from previous round's batched matvec
        if (tid < NH) {
            float g0 = bsum[tid],          g1 = bsum[NH + tid];
            float g2 = bsum[2 * NH + tid], g3 = bsum[3 * NH + tid];
            #pragma unroll
            for (int ks = 0; ks < 8; ++ks) {
                const float* q = gp + ks * 1536;
                g0 += q[tid];          g1 += q[NH + tid];
                g2 += q[2 * NH + tid]; g3 += q[3 * NH + tid];
            }
            float c = stf[FX_C + tid];
            float c2 = sigmf(g1) * c + sigmf(g0) * tanhf(g2);
            float h2 = sigmf(g3) * tanhf(c2);
            stf[FX_C + tid] = c2; stf[FX_H + tid] = h2; sh_h[tid] = h2;
        }
        __syncthreads();
        if (tid < 264) {
            const int l = tid >> 3, p = tid & 7;
            const float* wr = W_lin + (size_t)l * 1152 + p * 48;
            const float* hp = sh_h + p * 48;
            float a = 0.f;
            #pragma unroll
            for (int k = 0; k < 48; ++k) a += wr[k] * hp[k];
            sh_red[tid] = a;
        }
        __syncthreads();
        if (tid < NL) {
            float q = b_lin[tid];
            #pragma unroll
            for (int p = 0; p < 8; ++p) q += sh_red[tid * 8 + p];
            sh_hWb[tid] = q; stf[FX_HWB + tid] = q;
        }
    } else {
        if (tid < NH) sh_h[tid] = stf[FX_H + tid];
        if (tid < NL) sh_hWb[tid] = stf[FX_HWB + tid];
    }
    __syncthreads();

    // ---- scan (all 8 waves redundant; wave 0 writes outputs) ----
    int t = sti[IX_T], wlen = sti[IX_WLEN], nw = sti[IX_NW], npos = sti[IX_NPOS],
        plast = sti[IX_PLAST], lpe_pend = sti[IX_LPEP], lpe_eff = sti[IX_LPEE];
    int size = char_sizes[s]; if (size > NT) size = NT;
    const float* eWb = encW + (size_t)s * NT * NL;
    float* outb = out + (size_t)s * NT * NL;
    int evt_t = -1, evt_start = 0; float evt_den = 1.f;

    for (; t < size; ++t) {
        float ot = (lane < NL) ? tanhf(eWb[(size_t)t * NL + lane] + sh_hWb[lane]) : -INFINITY;
        float bv = ot; int bi = lane;
        #pragma unroll
        for (int d = 32; d; d >>= 1) {
            float ov = __shfl_xor(bv, d);
            int   oi = __shfl_xor(bi, d);
            if (ov > bv || (ov == bv && oi < bi)) { bv = ov; bi = oi; }
        }
        const int aid = bi;
        if (wave == 0 && lane < NL) outb[(size_t)t * NL + lane] = ot;  // raw logits
        const int issep = sh_issep[aid];
        const int wl_prev = wlen;
        int nw_new;
        if (issep) { npos += 1; nw_new = nw + 1; }
        else       { nw_new = (nw < 1) ? 1 : nw; }
        const int do_l = issep && (nw_new >= 2);
        if (issep && npos >= 2) lpe_pend = plast;
        if (issep) plast = sh_posid[aid];
        wlen = issep ? 1 : wlen + 1;
        nw = nw_new;
        if (do_l) {
            evt_t = t;
            evt_start = (t - wl_prev < 0) ? 0 : (t - wl_prev);
            evt_den = (float)((wl_prev < 1) ? 1 : wl_prev);
            if (lpe_pend >= 0) { lpe_eff = lpe_pend; lpe_pend = -1; }
            ++t;
            break;
        }
    }
    __syncthreads();

    if (evt_t >= 0) {
        if (tid < NH) {
            float avg = (pcb[(size_t)evt_t * NH + tid] - pcb[(size_t)evt_start * NH + tid]) / evt_den;
            float pv = (lpe_eff >= 0) ? pew[lpe_eff * NH + tid] : 0.f;
            stf[FX_XC + tid]      = tanhf(pv + avg + b_cmb[tid]);
            stf[FX_XC + NH + tid] = sh_h[tid];
        }
    }
    if (tid == 0) {
        sti[IX_T] = t; sti[IX_WLEN] = wlen; sti[IX_NW] = nw; sti[IX_NPOS] = npos;
        sti[IX_PLAST] = plast; sti[IX_LPEP] = lpe_pend; sti[IX_LPEE] = lpe_eff;
        sti[IX_PEND] = (evt_t >= 0) ? 1 : 0;
        if (evt_t < 0) { sti[IX_DONE] = 1; atomicAdd((int*)(ws + OFF_FLG), 1); }
    }
}

// ---- kB: batched matvec — gpart[s][ks][r] = sum_k WT[k][r] * xcat[s][k] ---
__global__ __launch_bounds__(256) void kB(float* __restrict__ ws) {
    if (*(const int*)(ws + OFF_FLG) >= NB) return;   // all sequences done
    const int bid = blockIdx.x, tid = threadIdx.x;
    const int ks = bid & 7;       // k-slice (XCD-stable: bid%8 ~ XCD)
    const int rg = bid >> 3;      // row group 0..5 (256 rows each)
    __shared__ float sx[96][16];
    for (int i = tid; i < 96 * 16; i += 256) {
        int s = i / 96, kk = i - s * 96;
        sx[kk][s] = ws[OFF_STATE + (size_t)s * ST_STRIDE + FX_XC + ks * 96 + kk];
    }
    __syncthreads();
    const float* wcol = ws + OFF_WT + (size_t)(ks * 96) * 1536 + rg * 256 + tid;
    float acc[16];
    #pragma unroll
    for (int s = 0; s < 16; ++s) acc[s] = 0.f;
    #pragma unroll 4
    for (int kk = 0; kk < 96; ++kk) {
        float wv = wcol[(size_t)kk * 1536];
        #pragma unroll
        for (int s = 0; s < 16; ++s) acc[s] += wv * sx[kk][s];
    }
    float* gpo = ws + OFF_GP;
    const int r = rg * 256 + tid;
    #pragma unroll
    for (int s = 0; s < 16; ++s)
        gpo[(size_t)s * 8 * 1536 + (size_t)ks * 1536 + r] = acc[s];
}

// ---- parallel log-softmax -------------------------------------------------
__global__ void k_post(float* __restrict__ out) {
    int row = blockIdx.x * 4 + (threadIdx.x >> 6);
    int lane = threadIdx.x & 63;
    if (row >= NB * NT) return;
    float* p = out + (size_t)row * NL;
    float x = (lane < NL) ? p[lane] : -INFINITY;
    float m = x;
    #pragma unroll
    for (int d = 32; d; d >>= 1) m = fmaxf(m, __shfl_xor(m, d));
    float e = (lane < NL) ? expf(x - m) : 0.f;
    float su = e;
    #pragma unroll
    for (int d = 32; d; d >>= 1) su += __shfl_xor(su, d);
    if (lane < NL) p[lane] = (x - m) - logf(su);
}

extern "C" void kernel_launch(void* const* d_in, const int* in_sizes, int n_in,
                              void* d_out, int out_size, void* d_ws, size_t ws_size,
                              hipStream_t stream) {
    const float* enc          = (const float*)d_in[0];
    const int*   char_sizes   = (const int*)d_in[1];
    const int*   label_is_sep = (const int*)d_in[2];
    const int*   label_pos_id = (const int*)d_in[3];
    const float* posEmb       = (const float*)d_in[4];
    const float* W_ih         = (const float*)d_in[5];
    const float* W_hh         = (const float*)d_in[6];
    const float* b_ih         = (const float*)d_in[7];
    const float* b_hh         = (const float*)d_in[8];
    const float* W_lin        = (const float*)d_in[9];
    const float* b_lin        = (const float*)d_in[10];
    const float* W_cmb        = (const float*)d_in[11];
    const float* b_cmb        = (const float*)d_in[12];
    float* out = (float*)d_out;
    float* ws  = (float*)d_ws;

    hipLaunchKernelGGL(k_prep, dim3(1024), dim3(256), 0, stream,
                       W_ih, W_hh, W_cmb, posEmb, ws);
    hipLaunchKernelGGL(k_encw, dim3((NB * NT * NL + 255) / 256), dim3(256), 0, stream,
                       enc, W_lin, ws);
    hipLaunchKernelGGL(k_encCmb, dim3(1024), dim3(384), 0, stream, enc, W_cmb, ws);
    hipLaunchKernelGGL(k_prefix, dim3((NB * NH + 255) / 256), dim3(256), 0, stream, ws);
    hipLaunchKernelGGL(k_init, dim3(1), dim3(1024), 0, stream,
                       b_ih, b_hh, W_lin, b_lin, ws);
    hipLaunchKernelGGL(k_fill, dim3((NB * NT * NL + 255) / 256), dim3(256), 0, stream, out);

    for (int r = 0; r < ROUNDS; ++r) {
        hipLaunchKernelGGL(kA, dim3(NB), dim3(512), 0, stream,
                           char_sizes, label_is_sep, label_pos_id,
                           W_lin, b_lin, b_cmb, ws, out);
        hipLaunchKernelGGL(kB, dim3(48), dim3(256), 0, stream, ws);
    }

    hipLaunchKernelGGL(k_post, dim3((NB * NT + 3) / 4), dim3(256), 0, stream, out);
}

// Round 8
// 7389.350 us; speedup vs baseline: 17.6826x; 1.5900x over previous
//
#include <hip/hip_runtime.h>
#include <math.h>

// ---------------------------------------------------------------------------
// Decoder_21371757265153 — v8: one-dispatch-per-event round decoder.
// Grid = 256 blocks = 16 sequences x 16 row-slices. Every block of a sequence
// redundantly runs the scalar scan (deterministic, identical results), builds
// xcat locally, matvecs its OWN 96-row / 295 KB weight slice, and applies
// gates for its own 24 j's (c is slice-private). Cross-block state (h slices,
// hWb partials, scan ints) crosses only KERNEL BOUNDARIES, double-buffered by
// round parity => zero intra-round races, zero spins, zero atomics.
// XCD locality: bid%8 == slice%8 -> each XCD L2 serves 2 slices (590 KB).
// 1024 rounds = worst-case event count (sep at every step). Done sequences
// exit in one int read (DONE written to both parity slots; monotone race).
// ---------------------------------------------------------------------------

namespace {
constexpr int NB = 16;
constexpr int NT = 1024;
constexpr int NE = 768;
constexpr int NH = 384;
constexpr int NL = 33;
constexpr int ROUNDS = 1024;
constexpr int NSLICE = 16;     // row-slices per sequence
constexpr int JS = 24;         // j's per slice
constexpr int RS = 96;         // rows per slice (4 gates x 24 j)

constexpr size_t OFF_SL   = 0;                         // WS[sl][k][96]
constexpr size_t N_SL     = (size_t)NSLICE * NE * RS;  // 1179648
constexpr size_t OFF_PEW  = OFF_SL + N_SL;             // posEmbW[32][384]
constexpr size_t N_PEW    = 32 * NH;
constexpr size_t OFF_ENCW = OFF_PEW + N_PEW;           // encW[16][1024][33]
constexpr size_t N_ENCW   = (size_t)NB * NT * NL;
constexpr size_t OFF_BS   = OFF_ENCW + N_ENCW;         // bsum[1536]
constexpr size_t OFF_PC   = OFF_BS + 2048;             // pc[16][1025][384]
constexpr size_t N_PC     = (size_t)NB * 1025 * NH;
constexpr size_t OFF_STATE = OFF_PC + N_PC;            // 16 x 4096 floats
constexpr size_t ST_STRIDE = 4096;
// per-sequence state layout (float offsets)
constexpr int SX_HWBP = 64;    // 2 slots x [16][36]   (64 .. 1216)
constexpr int SX_H    = 1280;  // 2 slots x 512        (1280 .. 2304)
constexpr int SX_C    = 2432;  // 384
// scan-state int indices (2 slots x 16 ints at float offset 0)
constexpr int IX_T = 0, IX_WLEN = 1, IX_NW = 2, IX_NPOS = 3, IX_PLAST = 4,
              IX_LPEP = 5, IX_LPEE = 6, IX_DONE = 7;
// total ws = OFF_STATE + 16*4096 = 8,097,792 floats = 32.4 MB (v5 proved >=33.3)
}

__device__ __forceinline__ float sigmf(float x) { return 1.0f / (1.0f + expf(-x)); }

// ---- WS[sl][k][96] + posEmbW ----------------------------------------------
// row rho = gate*24+jj  ->  global row = gate*384 + sl*24 + jj
__global__ void k_prep(const float* __restrict__ W_ih, const float* __restrict__ W_hh,
                       const float* __restrict__ W_cmb, const float* __restrict__ posEmb,
                       float* __restrict__ ws) {
    float* SL = ws + OFF_SL;
    float* pw = ws + OFF_PEW;
    const int n1 = (int)N_SL, n2 = (int)N_PEW;
    for (int i = blockIdx.x * blockDim.x + threadIdx.x; i < n1 + n2;
         i += gridDim.x * blockDim.x) {
        if (i < n1) {
            int sl = i / (NE * RS), rem = i % (NE * RS);
            int k = rem / RS, rho = rem % RS;
            int gate = rho / JS, jj = rho % JS;
            int grow = gate * NH + sl * JS + jj;
            SL[i] = (k < NH) ? W_ih[(size_t)grow * NH + k]
                             : W_hh[(size_t)grow * NH + (k - NH)];
        } else {
            int j3 = i - n1;
            int p = j3 / NH, j = j3 % NH;
            const float* pe = posEmb + p * 128;
            const float* wr = W_cmb + (size_t)j * 896;
            float a = 0.f;
            #pragma unroll 4
            for (int k = 0; k < 128; ++k) a += pe[k] * wr[k];
            pw[j3] = a;
        }
    }
}

// ---- encW[bt][l] = enc[bt,:] @ W_lin[l, 384:] -----------------------------
__global__ void k_encw(const float* __restrict__ enc, const float* __restrict__ W_lin,
                       float* __restrict__ ws) {
    float* encW = ws + OFF_ENCW;
    int gid = blockIdx.x * 256 + threadIdx.x;
    if (gid >= NB * NT * NL) return;
    int bt = gid / NL, l = gid % NL;
    const float4* e4 = (const float4*)(enc + (size_t)bt * NE);
    const float4* w4 = (const float4*)(W_lin + (size_t)l * 1152 + NH);
    float a0 = 0, a1 = 0, a2 = 0, a3 = 0;
    for (int k = 0; k < NE / 4; ++k) {
        float4 e = e4[k], w = w4[k];
        a0 += e.x * w.x; a1 += e.y * w.y; a2 += e.z * w.z; a3 += e.w * w.w;
    }
    encW[gid] = (a0 + a1) + (a2 + a3);
}

// ---- pc[b][t][j] = enc[b,t,:] @ W_cmb[j,128:]  (pre-prefix) ---------------
__global__ void k_encCmb(const float* __restrict__ enc, const float* __restrict__ W_cmb,
                         float* __restrict__ ws) {
    __shared__ float tile[16][NE];
    float* pc = ws + OFF_PC;
    int blk = blockIdx.x;
    int b = blk >> 6;
    int t0 = (blk & 63) * 16;
    for (int i = threadIdx.x; i < 16 * NE; i += 384) {
        int row = i / NE, k = i % NE;
        tile[row][k] = enc[((size_t)(b * NT + t0 + row)) * NE + k];
    }
    __syncthreads();
    int j = threadIdx.x;
    const float4* w4 = (const float4*)(W_cmb + (size_t)j * 896 + 128);
    float acc[16];
    #pragma unroll
    for (int r = 0; r < 16; ++r) acc[r] = 0.f;
    for (int q = 0; q < NE / 4; ++q) {
        float4 w = w4[q];
        #pragma unroll
        for (int r = 0; r < 16; ++r) {
            acc[r] += w.x * tile[r][q * 4] + w.y * tile[r][q * 4 + 1]
                    + w.z * tile[r][q * 4 + 2] + w.w * tile[r][q * 4 + 3];
        }
    }
    #pragma unroll
    for (int r = 0; r < 16; ++r)
        pc[((size_t)b * 1025 + t0 + r) * NH + j] = acc[r];
}

// ---- in-place exclusive prefix over t per (b,j) ---------------------------
__global__ void k_prefix(float* __restrict__ ws) {
    float* pc = ws + OFF_PC;
    int id = blockIdx.x * 256 + threadIdx.x;
    if (id >= NB * NH) return;
    int b = id / NH, j = id % NH;
    float* p = pc + ((size_t)b * 1025) * NH + j;
    float s = 0.f;
    for (int t = 0; t < NT; ++t) {
        float x = p[(size_t)t * NH];
        p[(size_t)t * NH] = s;
        s += x;
    }
    p[(size_t)NT * NH] = s;
}

// ---- init: slot-0 state for all sequences, bsum ---------------------------
__global__ void k_init(const float* __restrict__ b_ih, const float* __restrict__ b_hh,
                       const float* __restrict__ W_lin, const float* __restrict__ b_lin,
                       float* __restrict__ ws) {
    __shared__ float shh[NH], shc[NH], shw[NL];
    int tid = threadIdx.x;
    if (tid < NH) {
        float gi = b_ih[tid] + b_hh[tid];
        float gg = b_ih[2 * NH + tid] + b_hh[2 * NH + tid];
        float go = b_ih[3 * NH + tid] + b_hh[3 * NH + tid];
        float c = sigmf(gi) * tanhf(gg);
        float h = sigmf(go) * tanhf(c);
        shh[tid] = h; shc[tid] = c;
    }
    __syncthreads();
    if (tid < NL) {
        float a = b_lin[tid];
        for (int k = 0; k < NH; ++k) a += W_lin[(size_t)tid * 1152 + k] * shh[k];
        shw[tid] = a;
    }
    for (int i = tid; i < 4 * NH; i += 1024) ws[OFF_BS + i] = b_ih[i] + b_hh[i];
    __syncthreads();
    for (int s = 0; s < NB; ++s) {
        float* stf = ws + OFF_STATE + (size_t)s * ST_STRIDE;
        int* ii = (int*)stf;
        if (tid < 16) ii[tid] = (tid == IX_LPEP || tid == IX_LPEE) ? -1 : 0;
        if (tid >= 32 && tid < 32 + 576) {      // hWbp slot0: [16][36]
            int i2 = tid - 32, r = i2 / 36, l = i2 % 36;
            stf[SX_HWBP + i2] = (r == 0 && l < NL) ? (shw[l] - b_lin[l]) : 0.f;
        }
        if (tid < NH) { stf[SX_H + tid] = shh[tid]; stf[SX_C + tid] = shc[tid]; }
    }
}

// ---- zero output (invalid rows stay zero => log_softmax = -log 33) --------
__global__ void k_fill(float* __restrict__ out) {
    int i = blockIdx.x * 256 + threadIdx.x;
    if (i < NB * NT * NL) out[i] = 0.f;
}

// ---- k_round: one event per sequence per dispatch -------------------------
__global__ __launch_bounds__(384) void k_round(
    const int* __restrict__ char_sizes,
    const int* __restrict__ label_is_sep, const int* __restrict__ label_pos_id,
    const float* __restrict__ W_lin, const float* __restrict__ b_lin,
    const float* __restrict__ b_cmb, float* __restrict__ ws,
    float* __restrict__ out, const int slot) {

    const int bid = blockIdx.x;
    const int s = bid >> 4;        // sequence
    const int rh = bid & 15;       // row-slice (XCD = rh % 8)
    const int tid = threadIdx.x;
    const int lane = tid & 63;
    const int wave = tid >> 6;

    float* stf = ws + OFF_STATE + (size_t)s * ST_STRIDE;
    int* ir = (int*)stf + slot * 16;            // read slot
    int* iw = (int*)stf + (slot ^ 1) * 16;      // write slot
    if (ir[IX_DONE]) return;

    const float* hWbp_r = stf + SX_HWBP + slot * 576;
    float*       hWbp_w = stf + SX_HWBP + (slot ^ 1) * 576;
    const float* h_r    = stf + SX_H + slot * 512;
    float*       h_w    = stf + SX_H + (slot ^ 1) * 512;
    float*       cst    = stf + SX_C;

    const float* SLw  = ws + OFF_SL + (size_t)rh * (NE * RS);
    const float* pew  = ws + OFF_PEW;
    const float* encW = ws + OFF_ENCW;
    const float* bsum = ws + OFF_BS;
    const float* pcb  = ws + OFF_PC + (size_t)s * 1025 * NH;

    __shared__ float sh_hWb[40], sh_h[NH], sh_x[NE], sh_part[384], sh_g[RS], sh_h2[JS];
    __shared__ int sh_issep[NL], sh_posid[NL];

    if (tid < NL) {
        float a = b_lin[tid];
        #pragma unroll
        for (int i = 0; i < 16; ++i) a += hWbp_r[i * 36 + tid];
        sh_hWb[tid] = a;
        sh_issep[tid] = label_is_sep[tid];
        sh_posid[tid] = label_pos_id[tid];
    }
    sh_h[tid % NH] = h_r[tid % NH];            // 384 threads == NH
    float creg = (tid < JS) ? cst[rh * JS + tid] : 0.f;
    __syncthreads();

    // ---- scan (redundant in all 16 blocks; 6 waves redundant per block) ----
    int t = ir[IX_T], wlen = ir[IX_WLEN], nw = ir[IX_NW], npos = ir[IX_NPOS],
        plast = ir[IX_PLAST], lpe_pend = ir[IX_LPEP], lpe_eff = ir[IX_LPEE];
    int size = char_sizes[s]; if (size > NT) size = NT;
    const float* eWb = encW + (size_t)s * NT * NL;
    float* outb = out + (size_t)s * NT * NL;
    int evt_t = -1, evt_start = 0; float evt_den = 1.f;

    for (; t < size; ++t) {
        float ot = (lane < NL) ? tanhf(eWb[(size_t)t * NL + lane] + sh_hWb[lane]) : -INFINITY;
        float bv = ot; int bi = lane;
        #pragma unroll
        for (int d = 32; d; d >>= 1) {
            float ov = __shfl_xor(bv, d);
            int   oi = __shfl_xor(bi, d);
            if (ov > bv || (ov == bv && oi < bi)) { bv = ov; bi = oi; }
        }
        const int aid = bi;
        if (rh == 0 && wave == 0 && lane < NL) outb[(size_t)t * NL + lane] = ot;
        const int issep = sh_issep[aid];
        const int wl_prev = wlen;
        int nw_new;
        if (issep) { npos += 1; nw_new = nw + 1; }
        else       { nw_new = (nw < 1) ? 1 : nw; }
        const int do_l = issep && (nw_new >= 2);
        if (issep && npos >= 2) lpe_pend = plast;
        if (issep) plast = sh_posid[aid];
        wlen = issep ? 1 : wlen + 1;
        nw = nw_new;
        if (do_l) {
            evt_t = t;
            evt_start = (t - wl_prev < 0) ? 0 : (t - wl_prev);
            evt_den = (float)((wl_prev < 1) ? 1 : wl_prev);
            if (lpe_pend >= 0) { lpe_eff = lpe_pend; lpe_pend = -1; }
            ++t;
            break;
        }
    }

    if (evt_t < 0) {
        // sequence finished: mark DONE in BOTH slots (monotone, race-benign)
        if (rh == 0 && tid == 0) { iw[IX_DONE] = 1; ir[IX_DONE] = 1; }
        return;
    }

    // ---- xcat = [tanh(pv + avg + b_cmb), h]  (all 384 threads, one j each) --
    {
        const int j = tid;
        float avg = (pcb[(size_t)evt_t * NH + j] - pcb[(size_t)evt_start * NH + j]) / evt_den;
        float pv = (lpe_eff >= 0) ? pew[lpe_eff * NH + j] : 0.f;
        sh_x[j]      = tanhf(pv + avg + b_cmb[j]);
        sh_x[NH + j] = sh_h[j];
    }
    __syncthreads();

    // ---- matvec own slice: 96 rows x 768 k; thread = (kq, rho) -------------
    {
        const int rho = tid % RS, kq = tid / RS;   // 4 k-quarters x 96 rows
        const float* wp = SLw + (size_t)(kq * 192) * RS + rho;
        const float* xp = sh_x + kq * 192;
        float a0 = 0.f, a1 = 0.f, a2 = 0.f, a3 = 0.f;
        #pragma unroll 8
        for (int k = 0; k < 192; k += 4) {
            a0 += wp[(size_t)(k + 0) * RS] * xp[k + 0];
            a1 += wp[(size_t)(k + 1) * RS] * xp[k + 1];
            a2 += wp[(size_t)(k + 2) * RS] * xp[k + 2];
            a3 += wp[(size_t)(k + 3) * RS] * xp[k + 3];
        }
        sh_part[tid] = (a0 + a1) + (a2 + a3);
    }
    __syncthreads();
    if (tid < RS) {
        const int gate = tid / JS, jj = tid % JS;
        const int grow = gate * NH + rh * JS + jj;
        sh_g[tid] = ((sh_part[tid] + sh_part[RS + tid])
                   + (sh_part[2 * RS + tid] + sh_part[3 * RS + tid])) + bsum[grow];
    }
    __syncthreads();
    if (tid < JS) {
        float gi = sh_g[tid], gf = sh_g[JS + tid], gg = sh_g[2 * JS + tid], go = sh_g[3 * JS + tid];
        float c2 = sigmf(gf) * creg + sigmf(gi) * tanhf(gg);
        float h2 = sigmf(go) * tanhf(c2);
        cst[rh * JS + tid] = c2;
        h_w[rh * JS + tid] = h2;
        sh_h2[tid] = h2;
    }
    __syncthreads();
    if (tid < NL) {     // hWb partial for own 24 h-dims
        const float* wr = W_lin + (size_t)tid * 1152 + rh * JS;
        float a = 0.f;
        #pragma unroll
        for (int k = 0; k < JS; ++k) a += wr[k] * sh_h2[k];
        hWbp_w[rh * 36 + tid] = a;
    }
    if (rh == 0 && tid == 0) {
        iw[IX_T] = t; iw[IX_WLEN] = wlen; iw[IX_NW] = nw; iw[IX_NPOS] = npos;
        iw[IX_PLAST] = plast; iw[IX_LPEP] = lpe_pend; iw[IX_LPEE] = lpe_eff;
        iw[IX_DONE] = 0;
    }
}

// ---- parallel log-softmax -------------------------------------------------
__global__ void k_post(float* __restrict__ out) {
    int row = blockIdx.x * 4 + (threadIdx.x >> 6);
    int lane = threadIdx.x & 63;
    if (row >= NB * NT) return;
    float* p = out + (size_t)row * NL;
    float x = (lane < NL) ? p[lane] : -INFINITY;
    float m = x;
    #pragma unroll
    for (int d = 32; d; d >>= 1) m = fmaxf(m, __shfl_xor(m, d));
    float e = (lane < NL) ? expf(x - m) : 0.f;
    float su = e;
    #pragma unroll
    for (int d = 32; d; d >>= 1) su += __shfl_xor(su, d);
    if (lane < NL) p[lane] = (x - m) - logf(su);
}

extern "C" void kernel_launch(void* const* d_in, const int* in_sizes, int n_in,
                              void* d_out, int out_size, void* d_ws, size_t ws_size,
                              hipStream_t stream) {
    const float* enc          = (const float*)d_in[0];
    const int*   char_sizes   = (const int*)d_in[1];
    const int*   label_is_sep = (const int*)d_in[2];
    const int*   label_pos_id = (const int*)d_in[3];
    const float* posEmb       = (const float*)d_in[4];
    const float* W_ih         = (const float*)d_in[5];
    const float* W_hh         = (const float*)d_in[6];
    const float* b_ih         = (const float*)d_in[7];
    const float* b_hh         = (const float*)d_in[8];
    const float* W_lin        = (const float*)d_in[9];
    const float* b_lin        = (const float*)d_in[10];
    const float* W_cmb        = (const float*)d_in[11];
    const float* b_cmb        = (const float*)d_in[12];
    float* out = (float*)d_out;
    float* ws  = (float*)d_ws;

    hipLaunchKernelGGL(k_prep, dim3(1024), dim3(256), 0, stream,
                       W_ih, W_hh, W_cmb, posEmb, ws);
    hipLaunchKernelGGL(k_encw, dim3((NB * NT * NL + 255) / 256), dim3(256), 0, stream,
                       enc, W_lin, ws);
    hipLaunchKernelGGL(k_encCmb, dim3(1024), dim3(384), 0, stream, enc, W_cmb, ws);
    hipLaunchKernelGGL(k_prefix, dim3((NB * NH + 255) / 256), dim3(256), 0, stream, ws);
    hipLaunchKernelGGL(k_init, dim3(1), dim3(1024), 0, stream,
                       b_ih, b_hh, W_lin, b_lin, ws);
    hipLaunchKernelGGL(k_fill, dim3((NB * NT * NL + 255) / 256), dim3(256), 0, stream, out);

    for (int r = 0; r < ROUNDS; ++r) {
        hipLaunchKernelGGL(k_round, dim3(256), dim3(384), 0, stream,
                           char_sizes, label_is_sep, label_pos_id,
                           W_lin, b_lin, b_cmb, ws, out, r & 1);
    }

    hipLaunchKernelGGL(k_post, dim3((NB * NT + 3) / 4), dim3(256), 0, stream, out);
}